// Round 10
// baseline (351.772 us; speedup 1.0000x reference)
//
#include <hip/hip_runtime.h>
#include <hip/hip_bf16.h>
#include <stdint.h>
#include <type_traits>

typedef __attribute__((ext_vector_type(8))) short short8;
typedef __attribute__((ext_vector_type(4))) float f32x4;
typedef __attribute__((ext_vector_type(16))) float f32x16;
typedef __attribute__((ext_vector_type(4))) unsigned int uint4v;
typedef __attribute__((ext_vector_type(2))) unsigned int uint2v;

#define DEV static __device__ __forceinline__

DEV short bf16b(float f) {
  return __builtin_bit_cast(short, __float2bfloat16(f));
}
DEV float exp2a(float x){ float r; asm("v_exp_f32 %0, %1" : "=v"(r) : "v"(x)); return r; }
DEV unsigned cvtpk(float lo, float hi){ unsigned r; asm("v_cvt_pk_bf16_f32 %0, %1, %2" : "=v"(r) : "v"(lo), "v"(hi)); return r; }
// permlane32_swap BUILTIN (R8-verified). swap(a,b) -> { [a.lo|b.lo], [a.hi|b.hi] }.
DEV uint2v plswap(unsigned a, unsigned b){
  return __builtin_amdgcn_permlane32_swap(a, b, false, false);
}
// async global->LDS, 16B/lane. LDS dest is wave-uniform base + lane*16.
DEV void gload16(const void* g, void* l){
  __builtin_amdgcn_global_load_lds(
      (const __attribute__((address_space(1))) void*)g,
      (__attribute__((address_space(3))) void*)l, 16, 0, 0);
}

// ---------------- GEMM: C[m][n] = (sum_k A[m][k] * W[n][k] + bias[n]) * oscale ----
template<typename AT, typename OT>
__global__ __launch_bounds__(256)
void gemm_bt_kernel(const AT* __restrict__ A, const float* __restrict__ W,
                    const float* __restrict__ bias, OT* __restrict__ C,
                    int M, int N, int K, float oscale)
{
  __shared__ __align__(16) short As[128*32];
  __shared__ __align__(16) short Bs[128*32];
  const int t = threadIdx.x;
  const int lane = t & 63;
  const int wv = t >> 6;
  const int wr = wv >> 1, wc = wv & 1;
  const int l15 = lane & 15, lg = lane >> 4;
  const int m0 = blockIdx.x * 128;
  const int n0 = blockIdx.y * 128;

  f32x4 acc[4][4] = {};

  for (int k0 = 0; k0 < K; k0 += 32) {
    #pragma unroll
    for (int c = 0; c < 2; ++c) {
      const int e = t + c*256;
      const int row = e >> 2;
      const int col = (e & 3) * 8;
      const int byte = row*64 + ((col*2) ^ ((row&6)<<3));
      short8 va;
      if constexpr (std::is_same<AT,float>::value) {
        const float* src = A + (size_t)(m0+row)*K + k0 + col;
        f32x4 f0 = *(const f32x4*)src;
        f32x4 f1 = *(const f32x4*)(src+4);
        #pragma unroll
        for (int j=0;j<4;++j){ va[j]=bf16b(f0[j]); va[4+j]=bf16b(f1[j]); }
      } else {
        va = *(const short8*)(A + (size_t)(m0+row)*K + k0 + col);
      }
      *(short8*)((char*)As + byte) = va;
      const float* srcB = W + (size_t)(n0+row)*K + k0 + col;
      f32x4 g0 = *(const f32x4*)srcB;
      f32x4 g1 = *(const f32x4*)(srcB+4);
      short8 vb;
      #pragma unroll
      for (int j=0;j<4;++j){ vb[j]=bf16b(g0[j]); vb[4+j]=bf16b(g1[j]); }
      *(short8*)((char*)Bs + byte) = vb;
    }
    __syncthreads();
    short8 af[4], bfr[4];
    #pragma unroll
    for (int m=0;m<4;++m) {
      const int row = wr*64 + m*16 + l15;
      af[m] = *(const short8*)((const char*)As + row*64 + ((lg*16) ^ ((row&6)<<3)));
    }
    #pragma unroll
    for (int n=0;n<4;++n) {
      const int row = wc*64 + n*16 + l15;
      bfr[n] = *(const short8*)((const char*)Bs + row*64 + ((lg*16) ^ ((row&6)<<3)));
    }
    #pragma unroll
    for (int m=0;m<4;++m)
      #pragma unroll
      for (int n=0;n<4;++n)
        acc[m][n] = __builtin_amdgcn_mfma_f32_16x16x32_bf16(af[m], bfr[n], acc[m][n], 0, 0, 0);
    __syncthreads();
  }

  #pragma unroll
  for (int n=0;n<4;++n) {
    const int col = n0 + wc*64 + n*16 + l15;
    const float bv = bias[col];
    #pragma unroll
    for (int m=0;m<4;++m) {
      #pragma unroll
      for (int i=0;i<4;++i) {
        const int row = m0 + wr*64 + m*16 + lg*4 + i;
        const float val = (acc[m][n][i] + bv) * oscale;
        if constexpr (std::is_same<OT,float>::value) C[(size_t)row*N + col] = val;
        else                                         C[(size_t)row*N + col] = bf16b(val);
      }
    }
  }
}

// ---------------- V transpose: Vh[b*4096+s][h*64+dk] -> Vt[(b*16+h)*64+dk][s] ----
__global__ __launch_bounds__(256)
void transpose_v_kernel(const short* __restrict__ Vh, short* __restrict__ Vt)
{
  __shared__ short tile[64][65];
  const int t = threadIdx.x;
  const int bh = blockIdx.y, b = bh >> 4, h = bh & 15;
  const int s0 = blockIdx.x * 64;
  const int r = t >> 2;
  const int c = (t & 3) * 16;
  const short* src = Vh + (size_t)(b*4096 + s0 + r)*1024 + h*64 + c;
  short8 v0 = *(const short8*)src;
  short8 v1 = *(const short8*)(src + 8);
  #pragma unroll
  for (int j=0;j<8;++j){ tile[r][c+j]=v0[j]; tile[r][c+8+j]=v1[j]; }
  __syncthreads();
  short8 o0, o1;
  #pragma unroll
  for (int j=0;j<8;++j){ o0[j]=tile[c+j][r]; o1[j]=tile[c+8+j][r]; }
  short* dst = Vt + (size_t)(bh*64 + r)*4096 + s0 + c;
  *(short8*)dst = o0;
  *(short8*)(dst+8) = o1;
}

// ---------------- mask -> additive float ----------------
__global__ __launch_bounds__(256)
void maskprep_kernel(const int* __restrict__ mask, float* __restrict__ mf)
{
  const int i = blockIdx.x*256 + threadIdx.x;
  mf[i] = (mask[i] == 0) ? -1.0e9f : 0.0f;
}

// ---------------- Flash attention, swapped-QK 32x32 structure ----------------
// Grid (32 q-blocks, 32 bh). 256 thr = 4 waves; wave owns 32 q-rows (QBLK=128).
// K/V staged via global_load_lds (linear LDS dest, pre-swizzled global source);
// mask read from global MF (additive floats) straight into the S-accumulator.
// LDS ops/wave-tile: 8 K-frag + 8 V-frag ds_read_b128 only.
__global__ __launch_bounds__(256, 3)
void flash_kernel(const short* __restrict__ Qh, const short* __restrict__ Kh,
                  const short* __restrict__ Vt, const float* __restrict__ MF,
                  short* __restrict__ O)
{
  __shared__ __align__(16) char smem[32768];
  char* KsBufB = smem;               // [2][8192] bytes
  char* VsBufB = smem + 16384;       // [2][8192] bytes

  const int t = threadIdx.x;
  const int lane = t & 63, wv = t >> 6;
  const int l31 = lane & 31, hi = lane >> 5;
  const int rsw = (l31 & 7) << 4;
  const int bh = blockIdx.y, b = bh >> 4, h = bh & 15;
  const int q0 = blockIdx.x * 128;
  const bool lo = (lane < 32);

  // Q B-frags (already scaled by 0.125*log2e in the Q projection)
  short8 qf[4];
  {
    const short* qrow = Qh + (size_t)(b*4096 + q0 + wv*32 + l31)*1024 + h*64;
    #pragma unroll
    for (int ds=0; ds<4; ++ds)
      qf[ds] = *(const short8*)(qrow + ds*16 + hi*8);
  }
  const float* mrow = MF + (size_t)b*4096;

  // staging geometry: LDS linear (row*128 + sl*16), global col pre-swizzled
  const int E0 = wv*64 + lane, E1 = E0 + 256;
  const int r0 = E0 >> 3, g0s = ((E0 & 7) ^ (r0 & 7)) * 8;
  const int r1 = E1 >> 3, g1s = ((E1 & 7) ^ (r1 & 7)) * 8;
  const short* gK0 = Kh + (size_t)(b*4096 + r0)*1024 + h*64 + g0s;
  const short* gK1 = Kh + (size_t)(b*4096 + r1)*1024 + h*64 + g1s;
  const short* gV0 = Vt + (size_t)(bh*64 + r0)*4096 + g0s;
  const short* gV1 = Vt + (size_t)(bh*64 + r1)*4096 + g1s;
  char* lK0 = KsBufB + wv*1024;      // c=0 chunk; c=1 at +4096; buf1 at +8192
  char* lV0 = VsBufB + wv*1024;

  float m_run = -3.0e38f;
  float l_run = 0.0f;
  f32x16 oA[2] = {};

  // prologue: DMA tile 0 into buf0
  gload16(gK0, lK0);        gload16(gK1, lK0 + 4096);
  gload16(gV0, lV0);        gload16(gV1, lV0 + 4096);
  __syncthreads();

  for (int kt = 0; kt < 64; ++kt) {
    const int cur = kt & 1;
    const char* KsC = KsBufB + cur*8192;
    const char* VsC = VsBufB + cur*8192;

    // ---- DMA next tile into the back buffer (issued first, completes by barrier) ----
    if (kt + 1 < 64) {
      const size_t koff = (size_t)(kt+1) * 65536;   // 64 rows * 1024 shorts
      const int    voff = (kt+1) * 64;
      char* dK = lK0 + (cur^1)*8192;
      char* dV = lV0 + (cur^1)*8192;
      gload16(gK0 + koff, dK);  gload16(gK1 + koff, dK + 4096);
      gload16(gV0 + voff, dV);  gload16(gV1 + voff, dV + 4096);
    }

    // ---- mask quads from global (L1-resident), keys per C-layout ----
    f32x4 mq[2][4];
    #pragma unroll
    for (int kh=0;kh<2;++kh)
      #pragma unroll
      for (int rq=0;rq<4;++rq)
        mq[kh][rq] = *(const f32x4*)(mrow + kt*64 + kh*32 + rq*8 + hi*4);

    // ---- S accumulator init = additive mask ----
    f32x16 sA[2];
    #pragma unroll
    for (int kh=0;kh<2;++kh)
      #pragma unroll
      for (int rq=0;rq<4;++rq) {
        sA[kh][rq*4+0] = mq[kh][rq][0]; sA[kh][rq*4+1] = mq[kh][rq][1];
        sA[kh][rq*4+2] = mq[kh][rq][2]; sA[kh][rq*4+3] = mq[kh][rq][3];
      }

    // ---- S^T = K Q^T : lane holds q=l31, k over regs ----
    __builtin_amdgcn_s_setprio(1);
    #pragma unroll
    for (int ds=0; ds<4; ++ds) {
      short8 kf0 = *(const short8*)(KsC + l31*128       + ((ds*32 + hi*16) ^ rsw));
      short8 kf1 = *(const short8*)(KsC + (l31+32)*128  + ((ds*32 + hi*16) ^ rsw));
      sA[0] = __builtin_amdgcn_mfma_f32_32x32x16_bf16(kf0, qf[ds], sA[0], 0,0,0);
      sA[1] = __builtin_amdgcn_mfma_f32_32x32x16_bf16(kf1, qf[ds], sA[1], 0,0,0);
    }
    __builtin_amdgcn_s_setprio(0);

    // ---- online softmax (in-register, log2 domain) ----
    float mx[8];
    #pragma unroll
    for (int r=0;r<8;++r)
      mx[r] = fmaxf(fmaxf(sA[0][r], sA[0][r+8]), fmaxf(sA[1][r], sA[1][r+8]));
    #pragma unroll
    for (int s=4; s>0; s>>=1)
      #pragma unroll
      for (int r=0;r<4;++r) if (r < s) mx[r] = fmaxf(mx[r], mx[r+s]);
    float tmx = mx[0];
    {
      uint2v rr = plswap(__builtin_bit_cast(unsigned, tmx), __builtin_bit_cast(unsigned, tmx));
      const float cross = __builtin_bit_cast(float, lo ? rr[1] : rr[0]);
      tmx = fmaxf(tmx, cross);
    }

    // defer-max (T13)
    if (!__all(tmx <= m_run + 8.0f)) {
      const float mnew = fmaxf(m_run, tmx);
      const float sc = exp2a(m_run - mnew);
      m_run = mnew;
      l_run *= sc;
      #pragma unroll
      for (int n=0;n<2;++n)
        #pragma unroll
        for (int r=0;r<16;++r) oA[n][r] *= sc;
    }

    f32x4 lp = {0.f,0.f,0.f,0.f};
    #pragma unroll
    for (int kh=0;kh<2;++kh)
      #pragma unroll
      for (int r=0;r<16;++r) {
        const float p = exp2a(sA[kh][r] - m_run);
        sA[kh][r] = p;
        lp[r&3] += p;
      }
    l_run += (lp[0]+lp[1]) + (lp[2]+lp[3]);

    // ---- P -> bf16 B-frags via cvt_pk + permlane32_swap builtin ----
    unsigned w[4][4];
    #pragma unroll
    for (int tt=0; tt<4; ++tt) {
      const int kh = tt>>1, ro = (tt&1)*8;
      unsigned c01 = cvtpk(sA[kh][ro+0], sA[kh][ro+1]);
      unsigned c23 = cvtpk(sA[kh][ro+2], sA[kh][ro+3]);
      unsigned c45 = cvtpk(sA[kh][ro+4], sA[kh][ro+5]);
      unsigned c67 = cvtpk(sA[kh][ro+6], sA[kh][ro+7]);
      uint2v r02 = plswap(c01, c45);
      uint2v r13 = plswap(c23, c67);
      w[tt][0] = r02[0];
      w[tt][1] = r13[0];
      w[tt][2] = r02[1];
      w[tt][3] = r13[1];
    }

    // ---- O^T += V^T P^T ----
    __builtin_amdgcn_s_setprio(1);
    #pragma unroll
    for (int n=0;n<2;++n) {
      #pragma unroll
      for (int tt=0;tt<4;++tt) {
        short8 vf = *(const short8*)(VsC + (n*32+l31)*128 + ((tt*32 + hi*16) ^ rsw));
        uint4v wp = {w[tt][0], w[tt][1], w[tt][2], w[tt][3]};
        oA[n] = __builtin_amdgcn_mfma_f32_32x32x16_bf16(vf, __builtin_bit_cast(short8, wp), oA[n], 0,0,0);
      }
    }
    __builtin_amdgcn_s_setprio(0);

    __syncthreads();   // drains DMA (vmcnt) + orders buffer swap
  }

  // ---- epilogue ----
  {
    uint2v rl = plswap(__builtin_bit_cast(unsigned, l_run), __builtin_bit_cast(unsigned, l_run));
    l_run += __builtin_bit_cast(float, lo ? rl[1] : rl[0]);
  }
  const float inv = 1.0f / l_run;

  char* ot = smem + wv*4096;   // 4KB per wave (4 waves = 16KB)
  #pragma unroll
  for (int n=0;n<2;++n)
    #pragma unroll
    for (int rq=0;rq<4;++rq) {
      const unsigned w0 = cvtpk(oA[n][rq*4+0]*inv, oA[n][rq*4+1]*inv);
      const unsigned w1 = cvtpk(oA[n][rq*4+2]*inv, oA[n][rq*4+3]*inv);
      const int sl = n*4 + rq;
      const int byte = l31*128 + ((sl*16) ^ ((l31&7)<<4)) + hi*8;
      *(unsigned*)(ot + byte)     = w0;
      *(unsigned*)(ot + byte + 4) = w1;
    }
  asm volatile("s_waitcnt lgkmcnt(0)" ::: "memory");
  __builtin_amdgcn_sched_barrier(0);

  const int row = lane >> 1, half = lane & 1;
  const int orow = b*4096 + q0 + wv*32 + row;
  #pragma unroll
  for (int i=0;i<4;++i) {
    const int sl = half*4 + i;
    short8 vv = *(const short8*)(ot + row*128 + ((sl*16) ^ ((row&7)<<4)));
    *(short8*)(O + (size_t)orow*1024 + h*64 + half*32 + i*8) = vv;
  }
}

extern "C" void kernel_launch(void* const* d_in, const int* in_sizes, int n_in,
                              void* d_out, int out_size, void* d_ws, size_t ws_size,
                              hipStream_t stream)
{
  const float* q    = (const float*)d_in[0];
  const float* k    = (const float*)d_in[1];
  const float* v    = (const float*)d_in[2];
  const int*   mask = (const int*)d_in[3];
  const float* w_q  = (const float*)d_in[4];
  const float* b_q  = (const float*)d_in[5];
  const float* w_k  = (const float*)d_in[6];
  const float* b_k  = (const float*)d_in[7];
  const float* w_v  = (const float*)d_in[8];
  const float* b_v  = (const float*)d_in[9];
  const float* w_o  = (const float*)d_in[10];
  const float* b_o  = (const float*)d_in[11];
  float* out = (float*)d_out;

  char* ws = (char*)d_ws;
  const size_t SZ = (size_t)8192*1024*2;   // one bf16 [8192][1024] buffer
  short* QH = (short*)(ws);
  short* KH = (short*)(ws + SZ);
  short* OB = (short*)(ws + 2*SZ);         // V-proj output, then reused for attn out
  short* VT = (short*)(ws + 3*SZ);
  float* MF = (float*)(ws + 4*SZ);         // 8192 floats (32KB); ws>=64MB proven in R0
  short* VH = OB;

  const float QSCALE = 0.125f * 1.44269504f;

  dim3 bG(256);
  dim3 gG(64, 8);
  hipLaunchKernelGGL((gemm_bt_kernel<float, short>), gG, bG, 0, stream, q, w_q, b_q, QH, 8192, 1024, 1024, QSCALE);
  hipLaunchKernelGGL((gemm_bt_kernel<float, short>), gG, bG, 0, stream, k, w_k, b_k, KH, 8192, 1024, 1024, 1.0f);
  hipLaunchKernelGGL((gemm_bt_kernel<float, short>), gG, bG, 0, stream, v, w_v, b_v, VH, 8192, 1024, 1024, 1.0f);
  hipLaunchKernelGGL(transpose_v_kernel, dim3(64, 32), bG, 0, stream, VH, VT);
  hipLaunchKernelGGL(maskprep_kernel, dim3(32), bG, 0, stream, mask, MF);
  hipLaunchKernelGGL(flash_kernel, dim3(32, 32), bG, 0, stream, QH, KH, VT, MF, OB);
  hipLaunchKernelGGL((gemm_bt_kernel<short, float>), gG, bG, 0, stream, OB, w_o, b_o, out, 8192, 1024, 1024, 1.0f);
}

// Round 11
// 348.922 us; speedup vs baseline: 1.0082x; 1.0082x over previous
//
#include <hip/hip_runtime.h>
#include <hip/hip_bf16.h>
#include <stdint.h>
#include <type_traits>

typedef __attribute__((ext_vector_type(8))) short short8;
typedef __attribute__((ext_vector_type(4))) float f32x4;
typedef __attribute__((ext_vector_type(16))) float f32x16;
typedef __attribute__((ext_vector_type(4))) unsigned int uint4v;
typedef __attribute__((ext_vector_type(2))) unsigned int uint2v;

#define DEV static __device__ __forceinline__

DEV short bf16b(float f) {
  return __builtin_bit_cast(short, __float2bfloat16(f));
}
DEV float exp2a(float x){ float r; asm("v_exp_f32 %0, %1" : "=v"(r) : "v"(x)); return r; }
DEV unsigned cvtpk(float lo, float hi){ unsigned r; asm("v_cvt_pk_bf16_f32 %0, %1, %2" : "=v"(r) : "v"(lo), "v"(hi)); return r; }
// permlane32_swap BUILTIN (R8-verified). swap(a,b) -> { [a.lo|b.lo], [a.hi|b.hi] }.
DEV uint2v plswap(unsigned a, unsigned b){
  return __builtin_amdgcn_permlane32_swap(a, b, false, false);
}
// async global->LDS, 16B/lane. LDS dest is wave-uniform base + lane*16.
DEV void gload16(const void* g, void* l){
  __builtin_amdgcn_global_load_lds(
      (const __attribute__((address_space(1))) void*)g,
      (__attribute__((address_space(3))) void*)l, 16, 0, 0);
}

// ---------------- GEMM: C[m][n] = (sum_k A[m][k] * W[n][k] + bias[n]) * oscale ----
template<typename AT, typename OT>
__global__ __launch_bounds__(256)
void gemm_bt_kernel(const AT* __restrict__ A, const float* __restrict__ W,
                    const float* __restrict__ bias, OT* __restrict__ C,
                    int M, int N, int K, float oscale)
{
  __shared__ __align__(16) short As[128*32];
  __shared__ __align__(16) short Bs[128*32];
  const int t = threadIdx.x;
  const int lane = t & 63;
  const int wv = t >> 6;
  const int wr = wv >> 1, wc = wv & 1;
  const int l15 = lane & 15, lg = lane >> 4;
  const int m0 = blockIdx.x * 128;
  const int n0 = blockIdx.y * 128;

  f32x4 acc[4][4] = {};

  for (int k0 = 0; k0 < K; k0 += 32) {
    #pragma unroll
    for (int c = 0; c < 2; ++c) {
      const int e = t + c*256;
      const int row = e >> 2;
      const int col = (e & 3) * 8;
      const int byte = row*64 + ((col*2) ^ ((row&6)<<3));
      short8 va;
      if constexpr (std::is_same<AT,float>::value) {
        const float* src = A + (size_t)(m0+row)*K + k0 + col;
        f32x4 f0 = *(const f32x4*)src;
        f32x4 f1 = *(const f32x4*)(src+4);
        #pragma unroll
        for (int j=0;j<4;++j){ va[j]=bf16b(f0[j]); va[4+j]=bf16b(f1[j]); }
      } else {
        va = *(const short8*)(A + (size_t)(m0+row)*K + k0 + col);
      }
      *(short8*)((char*)As + byte) = va;
      const float* srcB = W + (size_t)(n0+row)*K + k0 + col;
      f32x4 g0 = *(const f32x4*)srcB;
      f32x4 g1 = *(const f32x4*)(srcB+4);
      short8 vb;
      #pragma unroll
      for (int j=0;j<4;++j){ vb[j]=bf16b(g0[j]); vb[4+j]=bf16b(g1[j]); }
      *(short8*)((char*)Bs + byte) = vb;
    }
    __syncthreads();
    short8 af[4], bfr[4];
    #pragma unroll
    for (int m=0;m<4;++m) {
      const int row = wr*64 + m*16 + l15;
      af[m] = *(const short8*)((const char*)As + row*64 + ((lg*16) ^ ((row&6)<<3)));
    }
    #pragma unroll
    for (int n=0;n<4;++n) {
      const int row = wc*64 + n*16 + l15;
      bfr[n] = *(const short8*)((const char*)Bs + row*64 + ((lg*16) ^ ((row&6)<<3)));
    }
    #pragma unroll
    for (int m=0;m<4;++m)
      #pragma unroll
      for (int n=0;n<4;++n)
        acc[m][n] = __builtin_amdgcn_mfma_f32_16x16x32_bf16(af[m], bfr[n], acc[m][n], 0, 0, 0);
    __syncthreads();
  }

  #pragma unroll
  for (int n=0;n<4;++n) {
    const int col = n0 + wc*64 + n*16 + l15;
    const float bv = bias[col];
    #pragma unroll
    for (int m=0;m<4;++m) {
      #pragma unroll
      for (int i=0;i<4;++i) {
        const int row = m0 + wr*64 + m*16 + lg*4 + i;
        const float val = (acc[m][n][i] + bv) * oscale;
        if constexpr (std::is_same<OT,float>::value) C[(size_t)row*N + col] = val;
        else                                         C[(size_t)row*N + col] = bf16b(val);
      }
    }
  }
}

// ---------------- V transpose: Vh[b*4096+s][h*64+dk] -> Vt[(b*16+h)*64+dk][s] ----
__global__ __launch_bounds__(256)
void transpose_v_kernel(const short* __restrict__ Vh, short* __restrict__ Vt)
{
  __shared__ short tile[64][65];
  const int t = threadIdx.x;
  const int bh = blockIdx.y, b = bh >> 4, h = bh & 15;
  const int s0 = blockIdx.x * 64;
  const int r = t >> 2;
  const int c = (t & 3) * 16;
  const short* src = Vh + (size_t)(b*4096 + s0 + r)*1024 + h*64 + c;
  short8 v0 = *(const short8*)src;
  short8 v1 = *(const short8*)(src + 8);
  #pragma unroll
  for (int j=0;j<8;++j){ tile[r][c+j]=v0[j]; tile[r][c+8+j]=v1[j]; }
  __syncthreads();
  short8 o0, o1;
  #pragma unroll
  for (int j=0;j<8;++j){ o0[j]=tile[c+j][r]; o1[j]=tile[c+8+j][r]; }
  short* dst = Vt + (size_t)(bh*64 + r)*4096 + s0 + c;
  *(short8*)dst = o0;
  *(short8*)(dst+8) = o1;
}

// ---------------- mask -> additive float ----------------
__global__ __launch_bounds__(256)
void maskprep_kernel(const int* __restrict__ mask, float* __restrict__ mf)
{
  const int i = blockIdx.x*256 + threadIdx.x;
  mf[i] = (mask[i] == 0) ? -1.0e9f : 0.0f;
}

// ---------------- Flash attention, swapped-QK 32x32 structure ----------------
// Grid (32 q-blocks, 32 bh). 256 thr = 4 waves; wave owns 32 q-rows (QBLK=128).
// K/V staged via global_load_lds (linear LDS, pre-swizzled global source).
// Mask prefetched into REGISTERS one tile ahead (loads issued at loop bottom,
// drained by the barrier) so the top-of-tile compute never waits on vmem —
// this was R9's regression: mask loads younger than the DMA forced vmcnt(0).
__global__ __launch_bounds__(256, 3)
void flash_kernel(const short* __restrict__ Qh, const short* __restrict__ Kh,
                  const short* __restrict__ Vt, const float* __restrict__ MF,
                  short* __restrict__ O)
{
  __shared__ __align__(16) char smem[32768];
  char* KsBufB = smem;               // [2][8192] bytes
  char* VsBufB = smem + 16384;       // [2][8192] bytes

  const int t = threadIdx.x;
  const int lane = t & 63, wv = t >> 6;
  const int l31 = lane & 31, hi = lane >> 5;
  const int rsw = (l31 & 7) << 4;
  const int bh = blockIdx.y, b = bh >> 4, h = bh & 15;
  const int q0 = blockIdx.x * 128;
  const bool lo = (lane < 32);

  // Q B-frags (already scaled by 0.125*log2e in the Q projection)
  short8 qf[4];
  {
    const short* qrow = Qh + (size_t)(b*4096 + q0 + wv*32 + l31)*1024 + h*64;
    #pragma unroll
    for (int ds=0; ds<4; ++ds)
      qf[ds] = *(const short8*)(qrow + ds*16 + hi*8);
  }
  const float* mrow = MF + (size_t)b*4096;

  // staging geometry: LDS linear (row*128 + sl*16), global col pre-swizzled
  const int E0 = wv*64 + lane, E1 = E0 + 256;
  const int r0 = E0 >> 3, g0s = ((E0 & 7) ^ (r0 & 7)) * 8;
  const int r1 = E1 >> 3, g1s = ((E1 & 7) ^ (r1 & 7)) * 8;
  const short* gK0 = Kh + (size_t)(b*4096 + r0)*1024 + h*64 + g0s;
  const short* gK1 = Kh + (size_t)(b*4096 + r1)*1024 + h*64 + g1s;
  const short* gV0 = Vt + (size_t)(bh*64 + r0)*4096 + g0s;
  const short* gV1 = Vt + (size_t)(bh*64 + r1)*4096 + g1s;
  char* lK0 = KsBufB + wv*1024;      // c=0 chunk; c=1 at +4096; buf1 at +8192
  char* lV0 = VsBufB + wv*1024;

  float m_run = -3.0e38f;
  float l_run = 0.0f;
  f32x16 oA[2] = {};
  f32x4 mq[2][4];

  // prologue: DMA tile 0 into buf0; mask tile 0 into regs
  gload16(gK0, lK0);        gload16(gK1, lK0 + 4096);
  gload16(gV0, lV0);        gload16(gV1, lV0 + 4096);
  #pragma unroll
  for (int kh=0;kh<2;++kh)
    #pragma unroll
    for (int rq=0;rq<4;++rq)
      mq[kh][rq] = *(const f32x4*)(mrow + kh*32 + rq*8 + hi*4);
  __syncthreads();

  for (int kt = 0; kt < 64; ++kt) {
    const int cur = kt & 1;
    const char* KsC = KsBufB + cur*8192;
    const char* VsC = VsBufB + cur*8192;
    const bool more = (kt + 1 < 64);

    // ---- DMA next tile into the back buffer (nothing below waits on it) ----
    if (more) {
      const size_t koff = (size_t)(kt+1) * 65536;   // 64 rows * 1024 shorts
      const int    voff = (kt+1) * 64;
      char* dK = lK0 + (cur^1)*8192;
      char* dV = lV0 + (cur^1)*8192;
      gload16(gK0 + koff, dK);  gload16(gK1 + koff, dK + 4096);
      gload16(gV0 + voff, dV);  gload16(gV1 + voff, dV + 4096);
    }

    // ---- S accumulator init = additive mask (from regs, zero wait) ----
    f32x16 sA[2];
    #pragma unroll
    for (int kh=0;kh<2;++kh)
      #pragma unroll
      for (int rq=0;rq<4;++rq) {
        sA[kh][rq*4+0] = mq[kh][rq][0]; sA[kh][rq*4+1] = mq[kh][rq][1];
        sA[kh][rq*4+2] = mq[kh][rq][2]; sA[kh][rq*4+3] = mq[kh][rq][3];
      }

    // ---- S^T = K Q^T : lane holds q=l31, k over regs ----
    __builtin_amdgcn_s_setprio(1);
    #pragma unroll
    for (int ds=0; ds<4; ++ds) {
      short8 kf0 = *(const short8*)(KsC + l31*128       + ((ds*32 + hi*16) ^ rsw));
      short8 kf1 = *(const short8*)(KsC + (l31+32)*128  + ((ds*32 + hi*16) ^ rsw));
      sA[0] = __builtin_amdgcn_mfma_f32_32x32x16_bf16(kf0, qf[ds], sA[0], 0,0,0);
      sA[1] = __builtin_amdgcn_mfma_f32_32x32x16_bf16(kf1, qf[ds], sA[1], 0,0,0);
    }
    __builtin_amdgcn_s_setprio(0);

    // ---- online softmax (in-register, log2 domain) ----
    float mx[8];
    #pragma unroll
    for (int r=0;r<8;++r)
      mx[r] = fmaxf(fmaxf(sA[0][r], sA[0][r+8]), fmaxf(sA[1][r], sA[1][r+8]));
    #pragma unroll
    for (int s=4; s>0; s>>=1)
      #pragma unroll
      for (int r=0;r<4;++r) if (r < s) mx[r] = fmaxf(mx[r], mx[r+s]);
    float tmx = mx[0];
    {
      uint2v rr = plswap(__builtin_bit_cast(unsigned, tmx), __builtin_bit_cast(unsigned, tmx));
      const float cross = __builtin_bit_cast(float, lo ? rr[1] : rr[0]);
      tmx = fmaxf(tmx, cross);
    }

    // defer-max (T13)
    if (!__all(tmx <= m_run + 8.0f)) {
      const float mnew = fmaxf(m_run, tmx);
      const float sc = exp2a(m_run - mnew);
      m_run = mnew;
      l_run *= sc;
      #pragma unroll
      for (int n=0;n<2;++n)
        #pragma unroll
        for (int r=0;r<16;++r) oA[n][r] *= sc;
    }

    f32x4 lp = {0.f,0.f,0.f,0.f};
    #pragma unroll
    for (int kh=0;kh<2;++kh)
      #pragma unroll
      for (int r=0;r<16;++r) {
        const float p = exp2a(sA[kh][r] - m_run);
        sA[kh][r] = p;
        lp[r&3] += p;
      }
    l_run += (lp[0]+lp[1]) + (lp[2]+lp[3]);

    // ---- P -> bf16 B-frags via cvt_pk + permlane32_swap builtin ----
    unsigned w[4][4];
    #pragma unroll
    for (int tt=0; tt<4; ++tt) {
      const int kh = tt>>1, ro = (tt&1)*8;
      unsigned c01 = cvtpk(sA[kh][ro+0], sA[kh][ro+1]);
      unsigned c23 = cvtpk(sA[kh][ro+2], sA[kh][ro+3]);
      unsigned c45 = cvtpk(sA[kh][ro+4], sA[kh][ro+5]);
      unsigned c67 = cvtpk(sA[kh][ro+6], sA[kh][ro+7]);
      uint2v r02 = plswap(c01, c45);
      uint2v r13 = plswap(c23, c67);
      w[tt][0] = r02[0];
      w[tt][1] = r13[0];
      w[tt][2] = r02[1];
      w[tt][3] = r13[1];
    }

    // ---- O^T += V^T P^T ----
    __builtin_amdgcn_s_setprio(1);
    #pragma unroll
    for (int n=0;n<2;++n) {
      #pragma unroll
      for (int tt=0;tt<4;++tt) {
        short8 vf = *(const short8*)(VsC + (n*32+l31)*128 + ((tt*32 + hi*16) ^ rsw));
        uint4v wp = {w[tt][0], w[tt][1], w[tt][2], w[tt][3]};
        oA[n] = __builtin_amdgcn_mfma_f32_32x32x16_bf16(vf, __builtin_bit_cast(short8, wp), oA[n], 0,0,0);
      }
    }
    __builtin_amdgcn_s_setprio(0);

    // ---- prefetch next tile's mask into regs (drained by the barrier) ----
    if (more) {
      #pragma unroll
      for (int kh=0;kh<2;++kh)
        #pragma unroll
        for (int rq=0;rq<4;++rq)
          mq[kh][rq] = *(const f32x4*)(mrow + (kt+1)*64 + kh*32 + rq*8 + hi*4);
    }

    __syncthreads();   // drains DMA + mask loads, orders buffer swap
  }

  // ---- epilogue ----
  {
    uint2v rl = plswap(__builtin_bit_cast(unsigned, l_run), __builtin_bit_cast(unsigned, l_run));
    l_run += __builtin_bit_cast(float, lo ? rl[1] : rl[0]);
  }
  const float inv = 1.0f / l_run;

  char* ot = smem + wv*4096;   // 4KB per wave (4 waves = 16KB)
  #pragma unroll
  for (int n=0;n<2;++n)
    #pragma unroll
    for (int rq=0;rq<4;++rq) {
      const unsigned w0 = cvtpk(oA[n][rq*4+0]*inv, oA[n][rq*4+1]*inv);
      const unsigned w1 = cvtpk(oA[n][rq*4+2]*inv, oA[n][rq*4+3]*inv);
      const int sl = n*4 + rq;
      const int byte = l31*128 + ((sl*16) ^ ((l31&7)<<4)) + hi*8;
      *(unsigned*)(ot + byte)     = w0;
      *(unsigned*)(ot + byte + 4) = w1;
    }
  asm volatile("s_waitcnt lgkmcnt(0)" ::: "memory");
  __builtin_amdgcn_sched_barrier(0);

  const int row = lane >> 1, half = lane & 1;
  const int orow = b*4096 + q0 + wv*32 + row;
  #pragma unroll
  for (int i=0;i<4;++i) {
    const int sl = half*4 + i;
    short8 vv = *(const short8*)(ot + row*128 + ((sl*16) ^ ((row&7)<<4)));
    *(short8*)(O + (size_t)orow*1024 + h*64 + half*32 + i*8) = vv;
  }
}

extern "C" void kernel_launch(void* const* d_in, const int* in_sizes, int n_in,
                              void* d_out, int out_size, void* d_ws, size_t ws_size,
                              hipStream_t stream)
{
  const float* q    = (const float*)d_in[0];
  const float* k    = (const float*)d_in[1];
  const float* v    = (const float*)d_in[2];
  const int*   mask = (const int*)d_in[3];
  const float* w_q  = (const float*)d_in[4];
  const float* b_q  = (const float*)d_in[5];
  const float* w_k  = (const float*)d_in[6];
  const float* b_k  = (const float*)d_in[7];
  const float* w_v  = (const float*)d_in[8];
  const float* b_v  = (const float*)d_in[9];
  const float* w_o  = (const float*)d_in[10];
  const float* b_o  = (const float*)d_in[11];
  float* out = (float*)d_out;

  char* ws = (char*)d_ws;
  const size_t SZ = (size_t)8192*1024*2;   // one bf16 [8192][1024] buffer
  short* QH = (short*)(ws);
  short* KH = (short*)(ws + SZ);
  short* OB = (short*)(ws + 2*SZ);         // V-proj output, then reused for attn out
  short* VT = (short*)(ws + 3*SZ);
  float* MF = (float*)(ws + 4*SZ);         // 8192 floats (32KB)
  short* VH = OB;

  const float QSCALE = 0.125f * 1.44269504f;

  dim3 bG(256);
  dim3 gG(64, 8);
  hipLaunchKernelGGL((gemm_bt_kernel<float, short>), gG, bG, 0, stream, q, w_q, b_q, QH, 8192, 1024, 1024, QSCALE);
  hipLaunchKernelGGL((gemm_bt_kernel<float, short>), gG, bG, 0, stream, k, w_k, b_k, KH, 8192, 1024, 1024, 1.0f);
  hipLaunchKernelGGL((gemm_bt_kernel<float, short>), gG, bG, 0, stream, v, w_v, b_v, VH, 8192, 1024, 1024, 1.0f);
  hipLaunchKernelGGL(transpose_v_kernel, dim3(64, 32), bG, 0, stream, VH, VT);
  hipLaunchKernelGGL(maskprep_kernel, dim3(32), bG, 0, stream, mask, MF);
  hipLaunchKernelGGL(flash_kernel, dim3(32, 32), bG, 0, stream, QH, KH, VT, MF, OB);
  hipLaunchKernelGGL((gemm_bt_kernel<short, float>), gG, bG, 0, stream, OB, w_o, b_o, out, 8192, 1024, 1024, 1.0f);
}